// Round 9
// baseline (93.371 us; speedup 1.0000x reference)
//
#include <hip/hip_runtime.h>
#include <stdint.h>

// out[t][n] = (sum_k q8(x[t]/sq)[k] * w8[n][k]) * a_scale[t] * (wclip[n]/127) + bias[n]
#define T_TOK 32768
#define NIN   1024
#define NOUT  1024

typedef int   v4i  __attribute__((ext_vector_type(4)));
typedef int   v16i __attribute__((ext_vector_type(16)));
typedef float v4f  __attribute__((ext_vector_type(4)));

#define MFMA_I8(a, b, c) __builtin_amdgcn_mfma_i32_32x32x32_i8(a, b, c, 0, 0, 0)

__device__ __forceinline__ void gload_lds16(const void* g, void* l) {
  __builtin_amdgcn_global_load_lds(
      (const __attribute__((address_space(1))) unsigned int*)g,
      (__attribute__((address_space(3))) unsigned int*)l, 16, 0, 0);
}

// Fragment layout (A and B): 16B chunk = (tile32*32 + ks)*64 + (row&31) + 32*h
// holding row's bytes k = ks*32 + h*16 .. +15. MFMA operand load for
// (tile32, ks) = one coalesced dwordx4 at base + lane*16. (r7/r8-verified)

// ---------------------------------------------------------------------------
// K0: repack weight (int32 [NOUT][NIN]) into fragment order. (verified)
// ---------------------------------------------------------------------------
__global__ __launch_bounds__(256) void repack_w_frag(const int* __restrict__ w,
                                                     uint32_t* __restrict__ wf) {
  const int gid  = blockIdx.x * 256 + threadIdx.x;
  const int lane = gid & 63;
  const int ks   = (gid >> 6) & 31;
  const int nt   = gid >> 11;
  const int n    = nt * 32 + (lane & 31);
  const int kb   = ks * 32 + (lane >> 5) * 16;
  const int* src = w + (size_t)n * NIN + kb;
  uint32_t d[4];
#pragma unroll
  for (int q = 0; q < 4; ++q) {
    const int4 v = ((const int4*)src)[q];
    d[q] = (uint32_t)(v.x & 0xff) | ((uint32_t)(v.y & 0xff) << 8) |
           ((uint32_t)(v.z & 0xff) << 16) | ((uint32_t)(v.w & 0xff) << 24);
  }
  ((uint4*)wf)[gid] = make_uint4(d[0], d[1], d[2], d[3]);
}

// ---------------------------------------------------------------------------
// K1: quant, 32 tokens/block (512 thr). r8-verified quant phase writes the
// swizzled LDS tile; new output stage emits fragment-ordered xq COALESCED
// (fixes r7's 4B-scatter): ds_read_b128 over XOR-permuted chunks
// (conflict-free) + lane-linear 16B global stores (1KB/instr).
// ---------------------------------------------------------------------------
__global__ __launch_bounds__(512) void quant2(const float* __restrict__ x,
                                              const float* __restrict__ sq,
                                              uint32_t* __restrict__ afw,
                                              float* __restrict__ asc) {
  __shared__ __align__(16) uint8_t Af[32 * NIN];   // 32 KiB

  const int tid  = threadIdx.x;
  const int lane = tid & 63;
  const int w    = tid >> 6;          // 0..7
  const int t0   = blockIdx.x * 32;

  {
    const v4f* sq4 = (const v4f*)sq;
    v4f rs[4];
#pragma unroll
    for (int j = 0; j < 4; ++j) {
      const v4f s = sq4[j * 64 + lane];
      rs[j].x = __builtin_amdgcn_rcpf(s.x);
      rs[j].y = __builtin_amdgcn_rcpf(s.y);
      rs[j].z = __builtin_amdgcn_rcpf(s.z);
      rs[j].w = __builtin_amdgcn_rcpf(s.w);
    }
#pragma unroll
    for (int i = 0; i < 4; ++i) {
      const int tl = w * 4 + i;                       // 0..31
      const v4f* xr = (const v4f*)(x + (size_t)(t0 + tl) * NIN);
      v4f v[4];
      float m = 0.f;
#pragma unroll
      for (int j = 0; j < 4; ++j) {
        v4f a = __builtin_nontemporal_load(&xr[j * 64 + lane]);
        a.x *= rs[j].x; a.y *= rs[j].y; a.z *= rs[j].z; a.w *= rs[j].w;
        v[j] = a;
        m = fmaxf(m, fmaxf(fmaxf(fabsf(a.x), fabsf(a.y)),
                           fmaxf(fabsf(a.z), fabsf(a.w))));
      }
#pragma unroll
      for (int off = 1; off < 64; off <<= 1) m = fmaxf(m, __shfl_xor(m, off));
      const float as = fmaxf(m * (1.f / 127.f), 1e-8f);
      if (lane == 0) asc[t0 + tl] = as;
      const float ia = __builtin_amdgcn_rcpf(as);
#pragma unroll
      for (int j = 0; j < 4; ++j) {
        const int q0 = (int)rintf(fminf(fmaxf(v[j].x * ia, -127.f), 127.f));
        const int q1 = (int)rintf(fminf(fmaxf(v[j].y * ia, -127.f), 127.f));
        const int q2 = (int)rintf(fminf(fmaxf(v[j].z * ia, -127.f), 127.f));
        const int q3 = (int)rintf(fminf(fmaxf(v[j].w * ia, -127.f), 127.f));
        const uint32_t d = (uint32_t)(q0 & 0xff) | ((uint32_t)(q1 & 0xff) << 8) |
                           ((uint32_t)(q2 & 0xff) << 16) | ((uint32_t)(q3 & 0xff) << 24);
        const int di   = j * 64 + lane;      // dword col 0..255
        const int ksw  = di >> 3;            // k-step 0..31
        const int h    = (di >> 2) & 1;      // 16B half
        const int slot = ((tl ^ (ksw & 7)) & 31) + 32 * h;
        *(uint32_t*)(&Af[(ksw * 64 + slot) * 16 + (di & 3) * 4]) = d;
      }
    }
  }
  __syncthreads();

  // output stage: 2048 chunks of 16B -> 4 per thread, coalesced.
  // global chunk cg = ks*64 + (tl&31) + 32h ; stored LDS chunk has low-5 bits
  // XORed with (ks&7) (inverse of the store swizzle).
  v4i* dst = (v4i*)afw + (size_t)blockIdx.x * 2048;
#pragma unroll
  for (int p = 0; p < 4; ++p) {
    const int cg = p * 512 + tid;
    const int ks = cg >> 6;
    const int lc = (cg & ~31) | ((cg ^ (ks & 7)) & 31);
    __builtin_nontemporal_store(*(const v4i*)(&Af[lc * 16]), &dst[cg]);
  }
}

// ---------------------------------------------------------------------------
// K2: fragment GEMM, tile 128t x 256n, 256 thr / 4 waves, 2 blocks/CU.
// A-tile (128 KB) staged in LDS in two 64KB K-halves via global_load_lds
// (fragment order is lane-linear -> no swizzle needed, conflict-free reads).
// B streamed global->reg, depth-2 ring (weight is L2-resident per XCD).
// Wave owns all 4 mt x 2 nt -> 8 accs (128 AGPR).
// ---------------------------------------------------------------------------
__global__ __launch_bounds__(256, 2) void gemm2(
    const uint8_t* __restrict__ af,     // fragment-ordered xq, 32 MB
    const uint8_t* __restrict__ wf,     // fragment-ordered weight, 1 MB
    const float* __restrict__ asc,      // [T_TOK]
    const float* __restrict__ wclip,    // [NOUT]
    const float* __restrict__ bias,     // [NOUT]
    float* __restrict__ out)            // [T_TOK][NOUT]
{
  __shared__ __align__(16) uint8_t As[64 * 1024];   // one K-half of A

  const int g   = blockIdx.x;           // 1024
  const int xcd = g & 7;
  const int j   = g >> 3;               // 0..127
  const int T   = xcd * 32 + (j >> 2);  // t-tile 0..255 (n-siblings same XCD)
  const int nb  = j & 3;                // 256-col slice 0..3

  const int tid  = threadIdx.x;
  const int lane = tid & 63;
  const int w    = tid >> 6;            // 0..3

  const uint8_t* Abase = af + ((size_t)(T * 4) << 15);          // 128 KB tile
  const uint8_t* Bb    = wf + ((size_t)(nb * 8 + w * 2) << 15) + lane * 16;

  auto stage_half = [&](int h) {
#pragma unroll
    for (int p = 0; p < 16; ++p) {
      const int off = p * 4096 + tid * 16;      // 0..65520, lane-linear
      const int mt  = off >> 14;
      const int inr = off & 16383;
      gload_lds16(Abase + mt * 32768 + h * 16384 + inr, As + off);
    }
  };
  auto ldA = [&](int mt, int ksl) -> v4i {      // ksl 0..15 within half
    return *(const v4i*)(As + (((mt * 16 + ksl) * 64) + lane) * 16);
  };
  auto ldB = [&](int ks, int ntl) -> v4i {      // ks 0..31 global
    return *(const v4i*)(Bb + ntl * 32768 + ks * 1024);
  };

  v16i acc[4][2] = {};
  v4i Bae[2], Bao[2];                            // even/odd-ks B ring

  stage_half(0);
  Bae[0] = ldB(0, 0); Bae[1] = ldB(0, 1);
  Bao[0] = ldB(1, 0); Bao[1] = ldB(1, 1);
  __syncthreads();                               // half 0 staged (drains vmcnt)

#define STEP(KSL, BREG, KN)                                                  \
  do {                                                                       \
    v4i a[4];                                                                \
    _Pragma("unroll") for (int mt = 0; mt < 4; ++mt) a[mt] = ldA(mt, (KSL)); \
    __builtin_amdgcn_s_setprio(1);                                           \
    _Pragma("unroll") for (int mt = 0; mt < 4; ++mt) {                       \
      acc[mt][0] = MFMA_I8(a[mt], BREG[0], acc[mt][0]);                      \
      acc[mt][1] = MFMA_I8(a[mt], BREG[1], acc[mt][1]);                      \
    }                                                                        \
    __builtin_amdgcn_s_setprio(0);                                           \
    if ((KN) < 32) { BREG[0] = ldB((KN), 0); BREG[1] = ldB((KN), 1); }       \
  } while (0)

#pragma unroll
  for (int h = 0; h < 2; ++h) {
    if (h == 1) {
      __syncthreads();          // all waves done reading half 0
      stage_half(1);
      __syncthreads();          // half 1 staged
    }
#pragma unroll
    for (int kp = 0; kp < 16; kp += 2) {
      const int ks = h * 16 + kp;
      STEP(kp,     Bae, ks + 2);
      STEP(kp + 1, Bao, ks + 3);
    }
  }
#undef STEP

  // epilogue: C/D col = lane&31 (n), row = (reg&3)+8*(reg>>2)+4*(lane>>5)
  const int hr = 4 * (lane >> 5);
#pragma unroll
  for (int mt = 0; mt < 4; ++mt) {
    const int t0 = T * 128 + mt * 32;
    float ascv[16];
#pragma unroll
    for (int reg = 0; reg < 16; ++reg)
      ascv[reg] = asc[t0 + (reg & 3) + 8 * (reg >> 2) + hr];
#pragma unroll
    for (int ntl = 0; ntl < 2; ++ntl) {
      const int n = nb * 256 + (w * 2 + ntl) * 32 + (lane & 31);
      const float wsc = wclip[n] * (1.f / 127.f);
      const float bs  = bias[n];
#pragma unroll
      for (int reg = 0; reg < 16; ++reg) {
        const int r = t0 + (reg & 3) + 8 * (reg >> 2) + hr;
        __builtin_nontemporal_store(
            (float)acc[mt][ntl][reg] * ascv[reg] * wsc + bs,
            &out[(size_t)r * NOUT + n]);
      }
    }
  }
}

// ---------------------------------------------------------------------------
extern "C" void kernel_launch(void* const* d_in, const int* in_sizes, int n_in,
                              void* d_out, int out_size, void* d_ws, size_t ws_size,
                              hipStream_t stream) {
  const float* x      = (const float*)d_in[0];
  const int*   weight = (const int*)d_in[1];
  const float* bias   = (const float*)d_in[2];
  const float* wclip  = (const float*)d_in[3];
  const float* sq     = (const float*)d_in[4];
  float* out = (float*)d_out;

  // ws: wf 1 MB | af (fragment xq) 32 MB | asc 128 KB
  uint8_t* ws = (uint8_t*)d_ws;
  uint32_t* wfrag = (uint32_t*)ws;
  uint32_t* afrag = (uint32_t*)(ws + (1u << 20));
  float*    ascp  = (float*)(ws + (1u << 20) + ((size_t)T_TOK * NIN));

  repack_w_frag<<<(NOUT * NIN / 16) / 256, 256, 0, stream>>>(weight, wfrag);
  quant2<<<T_TOK / 32, 512, 0, stream>>>(x, sq, afrag, ascp);
  gemm2<<<1024, 256, 0, stream>>>((const uint8_t*)afrag, (const uint8_t*)wfrag,
                                  ascp, wclip, bias, out);
}